// Round 5
// baseline (2185.116 us; speedup 1.0000x reference)
//
#include <hip/hip_runtime.h>

typedef _Float16 half8 __attribute__((ext_vector_type(8)));
typedef float    f32x4 __attribute__((ext_vector_type(4)));

#define B_   1024
#define T_   256
#define U_   512

// d_ws layout
static const size_t WHT_OFF = 0;                 // WhT fp16 [2048][512]   = 2 MB
static const size_t H_OFF   = 2u*1024*1024;      // h ping-pong fp16 [2][1024][512] = 2 MB
static const size_t CTR_OFF = 4u*1024*1024;      // counters [32][256] u32 = 32 KB

// Transpose + fp16-convert Wh: WhT[j][k] = Wh[k][j]
__global__ __launch_bounds__(512)
void prep_wht(const float* __restrict__ Wh, _Float16* __restrict__ WhT) {
  int j = blockIdx.x;   // 0..2047
  int k = threadIdx.x;  // 0..511
  WhT[(size_t)j*U_ + k] = (_Float16)Wh[(size_t)k*(4*U_) + j];
}

__device__ __forceinline__ float sigm(float x) { return 1.f/(1.f + __expf(-x)); }
__device__ __forceinline__ float tanhf_fast(float x) {
  float ax = fabsf(x);
  float e  = __expf(2.f*ax);
  float t  = 1.f - 2.f/(e + 1.f);
  return copysignf(t, x);
}

__device__ __forceinline__ unsigned long long ld_agent_u64(const void* p) {
  return __hip_atomic_load((const unsigned long long*)p,
                           __ATOMIC_RELAXED, __HIP_MEMORY_SCOPE_AGENT);
}
__device__ __forceinline__ void st_agent_u32(void* p, unsigned v) {
  __hip_atomic_store((unsigned*)p, v, __ATOMIC_RELAXED, __HIP_MEMORY_SCOPE_AGENT);
}
__device__ __forceinline__ unsigned ld_agent_u32(const void* p) {
  return __hip_atomic_load((const unsigned*)p, __ATOMIC_RELAXED, __HIP_MEMORY_SCOPE_AGENT);
}

// Persistent LSTM, split-phase pipelined halves.
// 256 WGs x 512 thr; WG (grp,jcw): rows [grp*64,+64) split into X=[+0,32) Y=[+32,64),
// u cols [jcw*32,+32). Wave w: gate g=w&3, col-half chw=w>>2. Wh slab in VGPRs.
// Per (phase,t) counter; producers: stores -> syncthreads(vmcnt drain) -> tid0 add;
// consumers: every thread polls (control-dep orders the sc1 data loads after detect).
__global__ __launch_bounds__(512, 1)
void lstm_persist(const float* __restrict__ prices,
                  const float* __restrict__ Wx,
                  const float* __restrict__ bias,
                  const float* __restrict__ Wd,
                  const float* __restrict__ bd,
                  const float* __restrict__ Wp,
                  const float* __restrict__ bp,
                  const _Float16* __restrict__ WhT,
                  _Float16* __restrict__ hbuf,      // [2][1024][512] fp16
                  unsigned int* __restrict__ ctr,   // [32][256]
                  float* __restrict__ out)          // [1024][32]
{
  __shared__ __align__(16) _Float16 hs[32][520];    // 33.3 KB (stride 1040 B)
  __shared__ __align__(16) float    gz[4][32][33];  // 16.9 KB (stride 33: <=2-way read, <=4-way write)
  __shared__ float ps[64];

  const int tid = threadIdx.x;
  const int b   = blockIdx.x;
  const int xcd  = b & 7;
  const int slot = b >> 3;
  const int grp  = xcd*2 + (slot & 1);
  const int jcw  = slot >> 1;         // 0..15
  const int row0 = grp * 64;
  const int u0   = jcw * 32;

  const int wv8 = tid >> 6;        // wave 0..7
  const int g   = wv8 & 3;         // gate
  const int chw = wv8 >> 2;        // column half
  const int ln  = tid & 15;
  const int qd  = (tid >> 4) & 3;

  // Wh slab -> B-fragments (64 VGPRs): B[k=kk*32+qd*8+j][n=ln]
  half8 bf[16];
  #pragma unroll
  for (int kk = 0; kk < 16; ++kk) {
    int col = g*U_ + u0 + chw*16 + ln;
    bf[kk] = *(const half8*)&WhT[(size_t)col*U_ + kk*32 + qd*8];
  }

  // gate-stage mapping: thread -> (row rX = tid>>4 within half, col pair cp = tid&15)
  const int rX = tid >> 4;         // 0..31
  const int cp = tid & 15;
  const int u  = u0 + cp*2;
  float wxv[4][2], bv[4][2];
  #pragma unroll
  for (int gg2 = 0; gg2 < 4; ++gg2)
    #pragma unroll
    for (int j = 0; j < 2; ++j) {
      wxv[gg2][j] = Wx[gg2*U_ + u + j];
      bv[gg2][j]  = bias[gg2*U_ + u + j];
    }

  float c[2][2];                   // [phase][col j]
  c[0][0] = c[0][1] = c[1][0] = c[1][1] = 0.f;

  unsigned int* ctrg = ctr + (grp*2)*T_;   // phase p -> ctrg[p*T_ + t]

  for (int t = 0; t < T_; ++t) {
    const size_t curb = (size_t)(t & 1)*(B_*U_);
    _Float16* hnxt = hbuf + (size_t)((t + 1) & 1)*(B_*U_);

    #pragma unroll
    for (int ph = 0; ph < 2; ++ph) {
      const _Float16* hcur = hbuf + curb + (size_t)(row0 + 32*ph)*U_;

      // ---- wait for peers' half-tile of h(t) (skip t=0: memset zeros) ----
      if (t > 0) {
        const unsigned* cc = &ctrg[ph*T_ + (t-1)];
        while (ld_agent_u32(cc) < 16u) __builtin_amdgcn_s_sleep(1);
      }
      if (ph == 0 && tid < 64) ps[tid] = prices[(size_t)(row0 + tid)*T_ + t];

      // ---- stage half h tile: 32 rows x 128 8B-chunks ----
      #pragma unroll
      for (int it = 0; it < 8; ++it) {
        int id = tid + it*512;     // 0..4095
        int r  = id >> 7;          // 0..31
        int ch = id & 127;
        unsigned long long v = ld_agent_u64(&hcur[(size_t)r*U_ + ch*4]);
        *(unsigned long long*)&hs[r][ch*4] = v;
      }
      __syncthreads();

      // ---- z = h_half @ Wh: gate g, cols [chw*16,+16), 32 rows, K=512 ----
      f32x4 acc[2];
      #pragma unroll
      for (int rt = 0; rt < 2; ++rt)
        #pragma unroll
        for (int r = 0; r < 4; ++r)
          acc[rt][r] = 0.f;

      #pragma unroll
      for (int kk = 0; kk < 16; ++kk) {
        #pragma unroll
        for (int rt = 0; rt < 2; ++rt) {
          half8 afr = *(const half8*)&hs[rt*16 + ln][kk*32 + qd*8];
          acc[rt] = __builtin_amdgcn_mfma_f32_16x16x32_f16(afr, bf[kk], acc[rt], 0, 0, 0);
        }
      }

      // ---- scatter z (C/D: row = qd*4+r, col = ln) ----
      #pragma unroll
      for (int rt = 0; rt < 2; ++rt)
        #pragma unroll
        for (int r = 0; r < 4; ++r)
          gz[g][rt*16 + qd*4 + r][chw*16 + ln] = acc[rt][r];
      __syncthreads();

      // ---- gate math; packed 2xfp16 sc1 store ----
      {
        float px = ps[rX + 32*ph];
        unsigned short hb[2];
        #pragma unroll
        for (int j = 0; j < 2; ++j) {
          float zi = gz[0][rX][cp*2+j] + px*wxv[0][j] + bv[0][j];
          float zf = gz[1][rX][cp*2+j] + px*wxv[1][j] + bv[1][j];
          float zg = gz[2][rX][cp*2+j] + px*wxv[2][j] + bv[2][j];
          float zo = gz[3][rX][cp*2+j] + px*wxv[3][j] + bv[3][j];
          float ig = sigm(zi), fg = sigm(zf), gg = tanhf_fast(zg), og = sigm(zo);
          float cn = fg*c[ph][j] + ig*gg;
          c[ph][j] = cn;
          _Float16 hh = (_Float16)(og*tanhf_fast(cn));
          hb[j] = __builtin_bit_cast(unsigned short, hh);
        }
        unsigned pk = (unsigned)hb[0] | ((unsigned)hb[1] << 16);
        st_agent_u32(&hnxt[(size_t)(row0 + 32*ph + rX)*U_ + u], pk);
      }

      // ---- drain stores (syncthreads waits vmcnt(0) per wave), then signal ----
      __syncthreads();
      if (tid == 0)
        __hip_atomic_fetch_add(&ctrg[ph*T_ + t], 1u, __ATOMIC_RELAXED, __HIP_MEMORY_SCOPE_AGENT);
    }
  }

  // ---- wait for the group's final h(256) (both halves) ----
  {
    const unsigned* c0 = &ctrg[0*T_ + (T_-1)];
    const unsigned* c1 = &ctrg[1*T_ + (T_-1)];
    while (ld_agent_u32(c0) < 16u) __builtin_amdgcn_s_sleep(1);
    while (ld_agent_u32(c1) < 16u) __builtin_amdgcn_s_sleep(1);
  }

  // ---- fused head: 4 rows: row0 + jcw*4 .. +4 ----
  {
    const _Float16* hfin = hbuf;                               // parity of t=256 is 0
    float*    xrow = (float*)&gz[0][0][0];                     // [4][64]
    _Float16* hrow = (_Float16*)((char*)&gz[0][0][0] + 1024);  // [4][512]

    {
      int fl = tid*4;      // 512 threads x 8B = 4 rows x 512 halves
      int r2 = fl >> 9;
      int of = fl & 511;
      unsigned long long v = ld_agent_u64(&hfin[(size_t)(row0 + jcw*4 + r2)*U_ + of]);
      *(unsigned long long*)&hrow[r2*U_ + of] = v;
    }
    __syncthreads();
    if (tid < 256) {
      int rr = tid >> 6;
      int kk = tid & 63;
      float a = bd[kk];
      for (int k2 = 0; k2 < U_; ++k2)
        a += (float)hrow[rr*U_ + k2] * Wd[(size_t)k2*64 + kk];
      a = fmaxf(a, 0.f);
      xrow[rr*64 + kk] = a;
    }
    __syncthreads();
    if (tid < 256 && (tid & 63) < 32) {
      int rr = tid >> 6;
      int kk = tid & 63;
      int brow = row0 + jcw*4 + rr;
      float o2 = bp[kk];
      #pragma unroll
      for (int j2 = 0; j2 < 64; ++j2)
        o2 += xrow[rr*64 + j2] * Wp[j2*32 + kk];
      out[(size_t)brow*32 + kk] = o2;
    }
  }
}

extern "C" void kernel_launch(void* const* d_in, const int* in_sizes, int n_in,
                              void* d_out, int out_size, void* d_ws, size_t ws_size,
                              hipStream_t stream) {
  (void)in_sizes; (void)n_in; (void)out_size; (void)ws_size;
  const float* prices = (const float*)d_in[0];
  const float* Wx     = (const float*)d_in[1];
  const float* Wh     = (const float*)d_in[2];
  const float* bias   = (const float*)d_in[3];
  const float* Wd     = (const float*)d_in[4];
  const float* bd     = (const float*)d_in[5];
  const float* Wp     = (const float*)d_in[6];
  const float* bp     = (const float*)d_in[7];

  char* ws = (char*)d_ws;
  _Float16* WhT      = (_Float16*)(ws + WHT_OFF);
  _Float16* hbuf     = (_Float16*)(ws + H_OFF);
  unsigned int* ctr  = (unsigned int*)(ws + CTR_OFF);

  hipMemsetAsync(hbuf, 0, (size_t)B_*U_*sizeof(_Float16), stream);
  hipMemsetAsync(ctr, 0, 32*T_*sizeof(unsigned int), stream);

  prep_wht<<<dim3(4*U_), dim3(U_), 0, stream>>>(Wh, WhT);
  lstm_persist<<<dim3(256), dim3(512), 0, stream>>>(prices, Wx, bias, Wd, bd, Wp, bp,
                                                    WhT, hbuf, ctr, (float*)d_out);
}

// Round 10
// 1877.476 us; speedup vs baseline: 1.1639x; 1.1639x over previous
//
#include <hip/hip_runtime.h>

typedef _Float16 half8 __attribute__((ext_vector_type(8)));
typedef float    f32x4 __attribute__((ext_vector_type(4)));
typedef unsigned int u32;
typedef unsigned long long u64;

#define B_   1024
#define T_   256
#define U_   512

// 32 groups x 8 WGs; group owns 32 batch rows, WG owns u-slice of 64.
#define PER_G  8
#define ROWS_G 32
#define U_WG   64

// d_ws layout
static const size_t WHT_OFF = 0;                 // WhT fp16 [2048][512] = 2 MB
static const size_t H_OFF   = 2u*1024*1024;      // h ping-pong fp16 [2][1024][512] = 2 MB
static const size_t CTR_OFF = 4u*1024*1024;      // ctr u32 [32][8]
static const size_t PT_OFF  = 4u*1024*1024 + 65536;  // pricesT f32 [256][1024] = 1 MB

__global__ __launch_bounds__(512)
void prep_wht(const float* __restrict__ Wh, _Float16* __restrict__ WhT) {
  int j = blockIdx.x;   // 0..2047
  int k = threadIdx.x;  // 0..511
  WhT[(size_t)j*U_ + k] = (_Float16)Wh[(size_t)k*(4*U_) + j];
}

__global__ __launch_bounds__(256)
void prep_pt(const float* __restrict__ prices, float* __restrict__ pricesT) {
  int t = blockIdx.x;                 // 0..255
  for (int r = threadIdx.x; r < B_; r += 256)
    pricesT[(size_t)t*B_ + r] = prices[(size_t)r*T_ + t];
}

__device__ __forceinline__ float sigm(float x) { return 1.f/(1.f + __expf(-x)); }
__device__ __forceinline__ float tanhf_fast(float x) {
  float ax = fabsf(x);
  float e  = __expf(2.f*ax);          // large ax -> inf -> t = 1 (safe)
  float t  = 1.f - 2.f/(e + 1.f);
  return copysignf(t, x);
}

// Agent-scope (IC-coherent) fine-grain ops — proven R4/R5; no bulk cache ops.
__device__ __forceinline__ u64 ld_agent_u64(const void* p) {
  return __hip_atomic_load((const u64*)p, __ATOMIC_RELAXED, __HIP_MEMORY_SCOPE_AGENT);
}
__device__ __forceinline__ void st_agent_u64(void* p, u64 v) {
  __hip_atomic_store((u64*)p, v, __ATOMIC_RELAXED, __HIP_MEMORY_SCOPE_AGENT);
}
__device__ __forceinline__ void st_agent_u32(void* p, u32 v) {
  __hip_atomic_store((u32*)p, v, __ATOMIC_RELAXED, __HIP_MEMORY_SCOPE_AGENT);
}
__device__ __forceinline__ u32 ld_agent_u32(const void* p) {
  return __hip_atomic_load((const u32*)p, __ATOMIC_RELAXED, __HIP_MEMORY_SCOPE_AGENT);
}

// Persistent LSTM: 256 WGs x 512 thr. WG (gid = b>>3, j = b&7):
// rows [gid*32,+32), u [j*64,+64).
// Wave w: gate g = w&3, col-half cph = w>>2 (cols [cph*32,+32)).
// Each wave: FULL K=512 chain (R4-verbatim arithmetic, no K-split),
// 2 row-tiles x 2 col-tiles, bf[16][2] = 128 VGPR resident.
// Exchange via agent(sc) ops at IC; flags ctr[gid][8], value = steps completed.
__global__ __launch_bounds__(512, 1)
void lstm_persist(const float* __restrict__ pricesT,
                  const float* __restrict__ Wx,
                  const float* __restrict__ bias,
                  const float* __restrict__ Wd,
                  const float* __restrict__ bd,
                  const float* __restrict__ Wp,
                  const float* __restrict__ bp,
                  const _Float16* __restrict__ WhT,
                  _Float16* __restrict__ hbuf,      // [2][1024][512]
                  u32* __restrict__ ctr,            // [32][8]
                  float* __restrict__ out)          // [1024][32]
{
  __shared__ __align__(16) _Float16 hs[ROWS_G][520];   // 33.3 KB
  __shared__ __align__(16) float    gz[4][ROWS_G][66]; // 33.8 KB (2-way max)
  __shared__ float ps[ROWS_G];

  const int tid = threadIdx.x;
  const int b   = blockIdx.x;
  const int gid = b >> 3;           // group 0..31
  const int j   = b & 7;            // WG within group
  const int row0 = gid * ROWS_G;
  const int u0   = j * U_WG;

  const int wv8 = tid >> 6;         // wave 0..7
  const int g   = wv8 & 3;          // gate 0..3
  const int cph = wv8 >> 2;         // col-half 0..1 (32 cols each)
  const int ln  = tid & 15;
  const int qd  = (tid >> 4) & 3;

  // ---- Wh slab -> B-fragments (128 VGPR): B[k = kk*32 + qd*8 + jj][n = ln] ----
  half8 bf[16][2];
  #pragma unroll
  for (int kk = 0; kk < 16; ++kk) {
    #pragma unroll
    for (int ct = 0; ct < 2; ++ct) {
      int gcol = g*U_ + u0 + cph*32 + ct*16 + ln;   // global gate-col
      bf[kk][ct] = *(const half8*)&WhT[(size_t)gcol*U_ + kk*32 + qd*8];
    }
  }

  // gate-stage mapping: thread owns (row = tid&31, u4 = (tid>>5)*4 .. +4)
  const int grow = tid & 31;
  const int gu4  = (tid >> 5) * 4;          // 0..60 step 4
  float wxv[4][4], bv[4][4];
  #pragma unroll
  for (int gg = 0; gg < 4; ++gg)
    #pragma unroll
    for (int jj = 0; jj < 4; ++jj) {
      int ug = u0 + gu4 + jj;
      wxv[gg][jj] = Wx[gg*U_ + ug];
      bv[gg][jj]  = bias[gg*U_ + ug];
    }

  float c[4];
  #pragma unroll
  for (int e = 0; e < 4; ++e) c[e] = 0.f;

  u32* const myfl = ctr + gid*PER_G;

  for (int t = 0; t < T_; ++t) {
    const _Float16* hcur = hbuf + (size_t)(t & 1)*(B_*U_) + (size_t)row0*U_;
    _Float16* hnxt = hbuf + (size_t)((t + 1) & 1)*(B_*U_);

    // ---- wait: all 8 peers posted h(t) (flag >= t); vectorized, wave 0 only ----
    if (wv8 == 0) {
      const int lane = tid & 63;
      bool ok;
      do {
        u32 v = (lane < PER_G) ? ld_agent_u32(&myfl[lane]) : 0xFFFFFFFFu;
        ok = (v >= (u32)t);
        if (!__all(ok)) { __builtin_amdgcn_s_sleep(1); ok = false; }
        else ok = true;
      } while (!ok);
      if (tid < ROWS_G) ps[tid] = pricesT[(size_t)t*B_ + row0 + tid];
    }
    __syncthreads();

    // ---- stage h tile: 32 rows x 512 halves = 4096 chunks of 8B ----
    #pragma unroll
    for (int it = 0; it < 8; ++it) {
      int id = tid + it*512;        // 0..4095
      int r  = id >> 7;             // row 0..31
      int ch = id & 127;            // 8B chunk
      u64 v = ld_agent_u64(&hcur[(size_t)r*U_ + ch*4]);
      *(u64*)&hs[r][ch*4] = v;
    }
    __syncthreads();

    // ---- z = h @ Wh: gate g, rows 32, cols [cph*32,+32), FULL K=512 chain ----
    f32x4 acc[2][2];
    #pragma unroll
    for (int rt = 0; rt < 2; ++rt)
      #pragma unroll
      for (int ct = 0; ct < 2; ++ct)
        #pragma unroll
        for (int r = 0; r < 4; ++r)
          acc[rt][ct][r] = 0.f;

    #pragma unroll
    for (int kk = 0; kk < 16; ++kk) {
      #pragma unroll
      for (int rt = 0; rt < 2; ++rt) {
        half8 afr = *(const half8*)&hs[rt*16 + ln][kk*32 + qd*8];  // A[m=ln][k=qd*8+jj]
        acc[rt][0] = __builtin_amdgcn_mfma_f32_16x16x32_f16(afr, bf[kk][0], acc[rt][0], 0, 0, 0);
        acc[rt][1] = __builtin_amdgcn_mfma_f32_16x16x32_f16(afr, bf[kk][1], acc[rt][1], 0, 0, 0);
      }
    }

    // ---- scatter z (C/D: row = qd*4+r, col = ln) ----
    #pragma unroll
    for (int rt = 0; rt < 2; ++rt)
      #pragma unroll
      for (int ct = 0; ct < 2; ++ct)
        #pragma unroll
        for (int r = 0; r < 4; ++r)
          gz[g][rt*16 + qd*4 + r][cph*32 + ct*16 + ln] = acc[rt][ct][r];
    __syncthreads();

    // ---- gate math (fp32); one packed 4xfp16 8B store per thread ----
    {
      float px = ps[grow];
      unsigned short hb[4];
      #pragma unroll
      for (int jj = 0; jj < 4; ++jj) {
        float zi = gz[0][grow][gu4+jj] + px*wxv[0][jj] + bv[0][jj];
        float zf = gz[1][grow][gu4+jj] + px*wxv[1][jj] + bv[1][jj];
        float zg = gz[2][grow][gu4+jj] + px*wxv[2][jj] + bv[2][jj];
        float zo = gz[3][grow][gu4+jj] + px*wxv[3][jj] + bv[3][jj];
        float ig = sigm(zi), fg = sigm(zf), gg = tanhf_fast(zg), og = sigm(zo);
        float cn = fg*c[jj] + ig*gg;
        c[jj] = cn;
        _Float16 hh = (_Float16)(og*tanhf_fast(cn));
        hb[jj] = __builtin_bit_cast(unsigned short, hh);
      }
      u64 pk = (u64)hb[0] | ((u64)hb[1] << 16) | ((u64)hb[2] << 32) | ((u64)hb[3] << 48);
      st_agent_u64(&hnxt[(size_t)(row0 + grow)*U_ + u0 + gu4], pk);
    }

    // ---- drain (syncthreads waits vmcnt(0) per wave), then post flag = t+1 ----
    __syncthreads();
    if (tid == 0) st_agent_u32(&myfl[j], (u32)(t + 1));
  }

  // ---- wait group's final h(256) ----
  if (wv8 == 0) {
    const int lane = tid & 63;
    bool ok;
    do {
      u32 v = (lane < PER_G) ? ld_agent_u32(&myfl[lane]) : 0xFFFFFFFFu;
      ok = (v >= (u32)T_);
      if (!__all(ok)) { __builtin_amdgcn_s_sleep(1); ok = false; }
      else ok = true;
    } while (!ok);
  }
  __syncthreads();

  // ---- fused head: 4 rows: row0 + j*4 .. +4 ----
  {
    const _Float16* hfin = hbuf;                                // parity of t=256 is 0
    float*    xrow = (float*)&gz[0][0][0];                      // [4][64]
    _Float16* hrow = (_Float16*)((char*)&gz[0][0][0] + 1024);   // [4][512]

    {
      int fl = tid*4;      // 512 thr x 8B = 4 rows x 512 halves
      int r2 = fl >> 9;
      int of = fl & 511;
      u64 v = ld_agent_u64(&hfin[(size_t)(row0 + j*4 + r2)*U_ + of]);
      *(u64*)&hrow[r2*U_ + of] = v;
    }
    __syncthreads();
    if (tid < 256) {
      int rr = tid >> 6;
      int kk = tid & 63;
      float a = bd[kk];
      for (int k2 = 0; k2 < U_; ++k2)
        a += (float)hrow[rr*U_ + k2] * Wd[(size_t)k2*64 + kk];
      a = fmaxf(a, 0.f);
      xrow[rr*64 + kk] = a;
    }
    __syncthreads();
    if (tid < 256 && (tid & 63) < 32) {
      int rr = tid >> 6;
      int kk = tid & 63;
      int brow = row0 + j*4 + rr;
      float o2 = bp[kk];
      #pragma unroll
      for (int j2 = 0; j2 < 64; ++j2)
        o2 += xrow[rr*64 + j2] * Wp[j2*32 + kk];
      out[(size_t)brow*32 + kk] = o2;
    }
  }
}

extern "C" void kernel_launch(void* const* d_in, const int* in_sizes, int n_in,
                              void* d_out, int out_size, void* d_ws, size_t ws_size,
                              hipStream_t stream) {
  (void)in_sizes; (void)n_in; (void)out_size; (void)ws_size;
  const float* prices = (const float*)d_in[0];
  const float* Wx     = (const float*)d_in[1];
  const float* Wh     = (const float*)d_in[2];
  const float* bias   = (const float*)d_in[3];
  const float* Wd     = (const float*)d_in[4];
  const float* bd     = (const float*)d_in[5];
  const float* Wp     = (const float*)d_in[6];
  const float* bp     = (const float*)d_in[7];

  char* ws = (char*)d_ws;
  _Float16* WhT  = (_Float16*)(ws + WHT_OFF);
  _Float16* hbuf = (_Float16*)(ws + H_OFF);
  u32* ctr       = (u32*)(ws + CTR_OFF);
  float* pricesT = (float*)(ws + PT_OFF);

  // zero initial h (buffer 0) and the flags (ws is re-poisoned before every launch)
  hipMemsetAsync(hbuf, 0, (size_t)B_*U_*sizeof(_Float16), stream);
  hipMemsetAsync(ctr, 0, 32*PER_G*sizeof(u32), stream);

  prep_wht<<<dim3(4*U_), dim3(U_), 0, stream>>>(Wh, WhT);
  prep_pt<<<dim3(T_), dim3(256), 0, stream>>>(prices, pricesT);
  lstm_persist<<<dim3(256), dim3(512), 0, stream>>>(pricesT, Wx, bias, Wd, bd, Wp, bp,
                                                    WhT, hbuf, ctr, (float*)d_out);
}